// Round 4
// baseline (239.821 us; speedup 1.0000x reference)
//
#include <hip/hip_runtime.h>
#include <hip/hip_fp16.h>
#include <math.h>

#define NEG_SLOPE 0.2f

__device__ __forceinline__ float sigm(float x) { return 1.0f / (1.0f + __expf(-x)); }
__device__ __forceinline__ float tanh_fast(float x) {
    float xc = fminf(fmaxf(x, -15.0f), 15.0f);
    float e2 = __expf(2.0f * xc);
    return (e2 - 1.0f) / (e2 + 1.0f);
}
__device__ __forceinline__ float lrelu(float x) { return (x > 0.0f) ? x : NEG_SLOPE * x; }

typedef _Float16 h2v __attribute__((ext_vector_type(2)));
__device__ __forceinline__ float fdot2h(h2v a, h2v b, float c) {
#if __has_builtin(__builtin_amdgcn_fdot2)
    return __builtin_amdgcn_fdot2(a, b, c, false);
#else
    return (float)a[0] * (float)b[0] + (float)a[1] * (float)b[1] + c;
#endif
}

// ---------------- K0: zero deg ----------------
__global__ void k_zero(int* __restrict__ deg, int N) {
    int i = blockIdx.x * 256 + threadIdx.x;
    if (i < N) deg[i] = 0;
}

// ---------------- K1: histogram of dst ----------------
__global__ void k_hist(const int* __restrict__ dst, int* __restrict__ deg, int E) {
    int e = blockIdx.x * 256 + threadIdx.x;
    if (e < E) atomicAdd(deg + dst[e], 1);
}

// ---------------- scan (3 kernels, multi-block) ----------------
__global__ __launch_bounds__(256) void k_scan1(const int* __restrict__ deg,
                                               int* __restrict__ blksum, int N) {
    __shared__ int s[256];
    int tid = threadIdx.x;
    int i = blockIdx.x * 256 + tid;
    int v = (i < N) ? deg[i] : 0;
    s[tid] = v;
    __syncthreads();
    #pragma unroll
    for (int off = 128; off > 0; off >>= 1) {
        if (tid < off) s[tid] += s[tid + off];
        __syncthreads();
    }
    if (tid == 0) blksum[blockIdx.x] = s[0];
}

__global__ __launch_bounds__(256) void k_scan2(const int* __restrict__ blksum,
                                               int* __restrict__ blkoff, int nb) {
    __shared__ int s[256];
    int tid = threadIdx.x;
    int v = (tid < nb) ? blksum[tid] : 0;
    s[tid] = v;
    __syncthreads();
    for (int off = 1; off < 256; off <<= 1) {
        int t = (tid >= off) ? s[tid - off] : 0;
        __syncthreads();
        s[tid] += t;
        __syncthreads();
    }
    if (tid < nb) blkoff[tid] = s[tid] - v;   // exclusive
}

__global__ __launch_bounds__(256) void k_scan3(const int* __restrict__ deg,
                                               const int* __restrict__ blkoff,
                                               int* __restrict__ rowptr,
                                               int* __restrict__ cursor, int N, int E) {
    __shared__ int s[256];
    int tid = threadIdx.x;
    int i = blockIdx.x * 256 + tid;
    int v = (i < N) ? deg[i] : 0;
    s[tid] = v;
    __syncthreads();
    for (int off = 1; off < 256; off <<= 1) {
        int t = (tid >= off) ? s[tid - off] : 0;
        __syncthreads();
        s[tid] += t;
        __syncthreads();
    }
    int excl = s[tid] - v + blkoff[blockIdx.x];
    if (i < N) { rowptr[i] = excl; cursor[i] = excl; }
    if (i == N - 1) rowptr[N] = E;
}

// ---------------- K3: scatter edges into CSR (by dst) ----------------
__global__ void k_scatter(const int* __restrict__ src, const int* __restrict__ dst,
                          int* __restrict__ cursor, int* __restrict__ csr_src, int E) {
    int e = blockIdx.x * 256 + threadIdx.x;
    if (e < E) {
        int pos = atomicAdd(cursor + dst[e], 1);
        csr_src[pos] = src[e];
    }
}

// ---------------- K4a: wa_src[k][h] ----------------
__global__ void k_pre(const float* __restrict__ W_gat, const float* __restrict__ a_src,
                      const float* __restrict__ a_dst, float* __restrict__ wa) {
    int tid = threadIdx.x;          // tid = k*8 + h
    int k = tid >> 3, h = tid & 7;
    float s1 = 0.0f, s2 = 0.0f;
    for (int c = 0; c < 32; ++c) {
        float wv = W_gat[k * 256 + h * 32 + c];
        s1 += wv * a_src[h * 32 + c];
        s2 += wv * a_dst[h * 32 + c];
    }
    wa[tid] = s1;
    wa[256 + tid] = s2;
}

// ---------------- K4b: asrc/adst = x @ wa ----------------
__global__ __launch_bounds__(256) void k_att(const float* __restrict__ x,
                                             const float* __restrict__ wa,
                                             float* __restrict__ asrc,
                                             float* __restrict__ adst) {
    __shared__ float xs[32 * 33];
    __shared__ float was[256], wad[256];
    int tid = threadIdx.x;
    int n0 = blockIdx.x * 32;
    for (int i = tid; i < 1024; i += 256) {
        int nl = i >> 5, k = i & 31;
        xs[nl * 33 + k] = x[(size_t)(n0 + nl) * 32 + k];
    }
    was[tid] = wa[tid];
    wad[tid] = wa[256 + tid];
    __syncthreads();
    int nl = tid >> 3, h = tid & 7;
    float s1 = 0.0f, s2 = 0.0f;
    #pragma unroll
    for (int k = 0; k < 32; ++k) {
        float xv = xs[nl * 33 + k];
        s1 += xv * was[k * 8 + h];
        s2 += xv * wad[k * 8 + h];
    }
    asrc[(size_t)(n0 + nl) * 8 + h] = s1;
    adst[(size_t)(n0 + nl) * 8 + h] = s2;
}

// ---------------- K5: GAT gather ----------------
__global__ __launch_bounds__(256) void k_gat(
    const int* __restrict__ rowptr, const int* __restrict__ csr_src,
    const float* __restrict__ asrc, const float* __restrict__ adst,
    const float* __restrict__ x, float* __restrict__ z, int N) {
    int w = (blockIdx.x * 256 + threadIdx.x) >> 6;
    int lane = threadIdx.x & 63;
    if (w >= N) return;
    int r0 = rowptr[w], r1 = rowptr[w + 1];
    int h = lane >> 3, kq = lane & 7;
    float ad = adst[w * 8 + h];
    float4 acc = make_float4(0.0f, 0.0f, 0.0f, 0.0f);
    float den = 0.0f;
    const float4* x4 = (const float4*)x;
    for (int i = r0; i < r1; ++i) {
        int s = csr_src[i];
        float ew = __expf(lrelu(asrc[s * 8 + h] + ad));
        float4 xv = x4[(size_t)s * 8 + kq];
        acc.x += ew * xv.x; acc.y += ew * xv.y;
        acc.z += ew * xv.z; acc.w += ew * xv.w;
        den += ew;
    }
    float inv = 1.0f / fmaxf(den, 1e-16f);
    float4 r = make_float4(acc.x * inv, acc.y * inv, acc.z * inv, acc.w * inv);
    ((float4*)z)[(size_t)w * 64 + lane] = r;
}

// ---------------- K5b: gatT[b][c][node] = z[node,:] @ M[:,c] + b_gat[c] ----------------
__global__ __launch_bounds__(256) void k_zw(
    const float* __restrict__ z, const float* __restrict__ W_gat,
    const float* __restrict__ b_gat, float* __restrict__ gatT, int N, int n_node) {
    int gw = (blockIdx.x * 256 + threadIdx.x) >> 6;  // 0..7999
    int lane = threadIdx.x & 63;
    int chalf = gw & 1;
    int nset = gw >> 1;                               // 0..3999
    int c = chalf * 16 + (lane & 15);
    int sl = lane >> 4;
    float wcol[64];
    #pragma unroll
    for (int i = 0; i < 64; ++i) {
        int k = i & 31, hh = sl * 2 + (i >> 5);
        wcol[i] = 0.125f * W_gat[k * 256 + hh * 32 + c];
    }
    float bg = b_gat[c];
    const float4* z4 = (const float4*)z;
    for (int it = 0; it < 8; ++it) {
        int n = nset * 8 + it;
        if (n >= N) break;
        float p = 0.0f;
        #pragma unroll
        for (int k4 = 0; k4 < 16; ++k4) {
            float4 zv = z4[(size_t)n * 64 + sl * 16 + k4];
            p += zv.x * wcol[4 * k4] + zv.y * wcol[4 * k4 + 1]
               + zv.z * wcol[4 * k4 + 2] + zv.w * wcol[4 * k4 + 3];
        }
        p += __shfl_xor(p, 16, 64);
        p += __shfl_xor(p, 32, 64);
        if (lane < 16) {
            int b = n / n_node, kk = n - b * n_node;
            gatT[((size_t)b * 32 + c) * n_node + kk] = p + bg;
        }
    }
}

// ---------------- K6a: transpose W_ih1 [128][n_node] -> Wt [n_node][128] ----------------
__global__ __launch_bounds__(256) void k_wt(const float* __restrict__ W,
                                            float* __restrict__ Wt, int n_node) {
    __shared__ float tle[32][33];
    int kt = blockIdx.x & 31;
    int gt = blockIdx.x >> 5;
    int tid = threadIdx.x;
    for (int i = tid; i < 1024; i += 256) {
        int gl = i >> 5, kl = i & 31;
        int g = gt * 32 + gl, k = kt * 32 + kl;
        tle[gl][kl] = (k < n_node) ? W[(size_t)g * n_node + k] : 0.0f;
    }
    __syncthreads();
    for (int i = tid; i < 1024; i += 256) {
        int kl = i >> 5, gl = i & 31;
        int k = kt * 32 + kl, g = gt * 32 + gl;
        if (k < n_node) Wt[(size_t)k * 128 + g] = tle[gl][kl];
    }
}

// ---------------- K6b: P1[t,b,g] = bias + dot(Wt[:, g], gatT[b][t][:]) ----------------
__global__ __launch_bounds__(256) void k_p1(
    const float* __restrict__ gatT, const float* __restrict__ Wt,
    const float* __restrict__ b_ih1, const float* __restrict__ b_hh1,
    float* __restrict__ P1, int n_node, int B) {
    __shared__ __align__(16) float Arow[2][1024];
    __shared__ __align__(16) float part[4][2][128];
    int blk = blockIdx.x;
    int b = blk >> 4;
    int tq = blk & 15;
    int tid = threadIdx.x;
    const float* A0 = gatT + ((size_t)b * 32 + tq * 2) * n_node;
    #pragma unroll
    for (int r = 0; r < 2; ++r)
        for (int i = tid; i < n_node; i += 256)
            Arow[r][i] = A0[(size_t)r * n_node + i];
    __syncthreads();

    int g4 = tid & 31;               // float4 column group: g = g4*4..+3
    int tloc = (tid >> 5) & 1;
    int ks = tid >> 6;               // wave id = k-quarter
    int kq = n_node >> 2;            // 250
    int k0 = ks * kq;
    const float4* Wt4 = (const float4*)Wt;
    float4 acc = make_float4(0.0f, 0.0f, 0.0f, 0.0f);
    #pragma unroll 4
    for (int k = 0; k < kq; ++k) {
        float4 w = Wt4[(size_t)(k0 + k) * 32 + g4];
        float a = Arow[tloc][k0 + k];
        acc.x += w.x * a; acc.y += w.y * a;
        acc.z += w.z * a; acc.w += w.w * a;
    }
    *(float4*)&part[ks][tloc][g4 * 4] = acc;
    __syncthreads();

    int tl = tid >> 7, g = tid & 127;
    float s = part[0][tl][g] + part[1][tl][g] + part[2][tl][g] + part[3][tl][g]
            + b_ih1[g] + b_hh1[g];
    int t = tq * 2 + tl;
    P1[((size_t)t * B + b) * 128 + g] = s;
}

// ---------------- K7: pipelined LSTM1 || LSTM2 ----------------
// 640 threads = 10 waves. Waves 0-1 (tid<128): LSTM1 gate rows. Waves 2-9
// (tid2=tid-128 in [0,512)): LSTM2, thread owns full gate row g_idx =
// (tid2&3)*128 + (tid2>>2); the 4 gates of hidden unit n sit in adjacent
// lanes -> 3 shfl_xor combine (R1-proven mapping). LSTM2 step t2 = s-1 runs
// concurrently with LSTM1 step s (it only needs h1[s-1]); input projection
// P2 is computed on the fly (32 MACs) so no P2 phase / buffer at all.
// Serial span: 33 supersteps x 2 barriers (was 64 + 33 sequential steps).
__global__ __launch_bounds__(640) void k_lstm(
    const float* __restrict__ P1, const float* __restrict__ W_hh1,
    const float* __restrict__ W_ih2, const float* __restrict__ W_hh2,
    const float* __restrict__ b_ih2, const float* __restrict__ b_hh2,
    float* __restrict__ h2finT, int B, int T) {
    __shared__ __align__(16) float P1s[32][128];     // 16KB
    __shared__ __align__(16) float h1s[32];
    __shared__ __align__(16) float g1s[128];
    __shared__ __align__(16) float h1all[32][32];    // 4KB
    __shared__ __align__(16) __half hbuf[2][128];
    int tid = threadIdx.x, b = blockIdx.x;

    for (int i = tid; i < 4096; i += 640) {
        int t = i >> 7, g = i & 127;
        P1s[t][g] = P1[((size_t)t * B + b) * 128 + g];
    }

    // L1 weights (waves 0-1)
    float4 w1[8];
    if (tid < 128) {
        const float4* W = (const float4*)(W_hh1 + (size_t)tid * 32);
        #pragma unroll
        for (int j = 0; j < 8; ++j) w1[j] = W[j];
    }

    // L2 weights (waves 2-9): full row g_idx in fp16 regs + W_ih2 row + bias
    int tid2 = tid - 128;
    int gt = tid2 & 3, n = tid2 >> 2;
    int g_idx = gt * 128 + n;
    h2v wh[64];
    float4 wi[8];
    float bias = 0.0f;
    if (tid >= 128) {
        const float4* Wr = (const float4*)(W_hh2 + (size_t)g_idx * 128);
        #pragma unroll
        for (int j = 0; j < 32; ++j) {
            float4 w = Wr[j];
            h2v t0, t1;
            t0[0] = (_Float16)w.x; t0[1] = (_Float16)w.y;
            t1[0] = (_Float16)w.z; t1[1] = (_Float16)w.w;
            wh[2 * j] = t0;
            wh[2 * j + 1] = t1;
        }
        const float4* Wi = (const float4*)(W_ih2 + (size_t)g_idx * 32);
        #pragma unroll
        for (int j = 0; j < 8; ++j) wi[j] = Wi[j];
        bias = b_ih2[g_idx] + b_hh2[g_idx];
    }

    if (tid < 32) h1s[tid] = 0.0f;
    if (tid >= 128 && tid < 256) hbuf[0][tid - 128] = __float2half(0.0f);
    float c1 = 0.0f, c2 = 0.0f;
    __syncthreads();

    for (int s = 0; s <= T; ++s) {
        // ---- phase A: L1 gate-dot (step s) || L2 full step (t2 = s-1) ----
        if (tid < 128) {
            if (s < T) {
                float acc = P1s[s][tid];
                const float4* hp = (const float4*)h1s;
                #pragma unroll
                for (int j = 0; j < 8; ++j) {
                    float4 h = hp[j], w = w1[j];
                    acc += w.x * h.x + w.y * h.y + w.z * h.z + w.w * h.w;
                }
                g1s[tid] = acc;
            }
        } else if (s >= 1) {
            int t2 = s - 1;
            // input projection on the fly (h1all[t2] broadcast reads)
            const float4* hp1 = (const float4*)h1all[t2];
            float p = bias;
            #pragma unroll
            for (int j = 0; j < 8; ++j) {
                float4 w = wi[j], h = hp1[j];
                p += w.x * h.x + w.y * h.y + w.z * h.z + w.w * h.w;
            }
            // recurrent 128-dot in fp16
            const uint4* hc4 = (const uint4*)hbuf[t2 & 1];
            float a0 = 0.0f, a1 = 0.0f, a2 = 0.0f, a3 = 0.0f;
            #pragma unroll
            for (int j = 0; j < 16; ++j) {
                uint4 hv = hc4[j];
                const h2v* hp = reinterpret_cast<const h2v*>(&hv);
                a0 = fdot2h(wh[4 * j],     hp[0], a0);
                a1 = fdot2h(wh[4 * j + 1], hp[1], a1);
                a2 = fdot2h(wh[4 * j + 2], hp[2], a2);
                a3 = fdot2h(wh[4 * j + 3], hp[3], a3);
            }
            float acc = p + ((a0 + a1) + (a2 + a3));
            float v1 = __shfl_xor(acc, 1, 64);
            float v2 = __shfl_xor(acc, 2, 64);
            float v3 = __shfl_xor(acc, 3, 64);
            if (gt == 0) {
                float i_ = sigm(acc), f_ = sigm(v1);
                float g_ = tanh_fast(v2), o_ = sigm(v3);
                c2 = f_ * c2 + i_ * g_;
                float h = o_ * tanh_fast(c2);
                hbuf[(t2 + 1) & 1][n] = __float2half(h);
                if (t2 == T - 1) h2finT[n * 32 + b] = h;
            }
        }
        __syncthreads();
        // ---- phase B: L1 elementwise update ----
        if (tid < 32 && s < T) {
            float i_ = sigm(g1s[tid]), f_ = sigm(g1s[32 + tid]);
            float g_ = tanh_fast(g1s[64 + tid]), o_ = sigm(g1s[96 + tid]);
            c1 = f_ * c1 + i_ * g_;
            float h = o_ * tanh_fast(c1);
            h1s[tid] = h;
            h1all[s][tid] = h;
        }
        __syncthreads();
    }
}

// ---------------- K8: final linear from h2finT ----------------
__global__ __launch_bounds__(256) void k_fin(
    const float* __restrict__ h2finT, const float* __restrict__ W_lin,
    const float* __restrict__ b_lin, float* __restrict__ out, int n_node, int B) {
    __shared__ __align__(16) float hs[128];
    int b = blockIdx.x >> 3;
    int kc = blockIdx.x & 7;
    int tid = threadIdx.x;
    if (tid < 128) hs[tid] = h2finT[tid * 32 + b];
    __syncthreads();
    int outdim = n_node * 2;
    int kk = kc * 256 + tid;
    if (kk < outdim) {
        float acc = b_lin[kk];
        const float4* W4 = (const float4*)(W_lin + (size_t)kk * 128);
        const float4* h4 = (const float4*)hs;
        #pragma unroll 8
        for (int j = 0; j < 32; ++j) {
            float4 w = W4[j], h = h4[j];
            acc += w.x * h.x + w.y * h.y + w.z * h.z + w.w * h.w;
        }
        out[(size_t)b * outdim + kk] = acc;
    }
}

extern "C" void kernel_launch(void* const* d_in, const int* in_sizes, int n_in,
                              void* d_out, int out_size, void* d_ws, size_t ws_size,
                              hipStream_t stream) {
    const float* x     = (const float*)d_in[0];
    const int*   src   = (const int*)d_in[1];
    const int*   dst   = (const int*)d_in[2];
    const float* W_gat = (const float*)d_in[4];
    const float* a_src = (const float*)d_in[5];
    const float* a_dst = (const float*)d_in[6];
    const float* b_gat = (const float*)d_in[7];
    const float* W_ih1 = (const float*)d_in[8];
    const float* W_hh1 = (const float*)d_in[9];
    const float* b_ih1 = (const float*)d_in[10];
    const float* b_hh1 = (const float*)d_in[11];
    const float* W_ih2 = (const float*)d_in[12];
    const float* W_hh2 = (const float*)d_in[13];
    const float* b_ih2 = (const float*)d_in[14];
    const float* b_hh2 = (const float*)d_in[15];
    const float* W_lin = (const float*)d_in[16];
    const float* b_lin = (const float*)d_in[17];

    int N = in_sizes[0] / 32;          // 32000
    int E = in_sizes[1];               // 384000
    int n_node = in_sizes[8] / 128;    // 1000
    int B = N / n_node;                // 32
    int T = 32;

    float* ws = (float*)d_ws;
    float* z      = ws;                                 // N*256
    float* asrc   = z + (size_t)N * 256;                // N*8
    float* adst   = asrc + (size_t)N * 8;               // N*8
    float* gatT   = adst + (size_t)N * 8;               // N*32
    float* P1     = gatT + (size_t)N * 32;              // T*B*128
    float* h1g    = P1 + (size_t)T * B * 128;           // B*1024 (unused, layout kept)
    float* P2g    = h1g + (size_t)B * 1024;             // B*16384 (unused, layout kept)
    float* h2finT = P2g + (size_t)B * 16384;            // 128*32
    float* wa     = h2finT + 128 * 32;                  // 512
    int* deg     = (int*)(wa + 512);                    // N
    int* cursor  = deg + N;                             // N
    int* rowptr  = cursor + N;                          // N+1
    int* csr_src = rowptr + N + 1;                      // E
    int* blksum  = csr_src + E;                         // 256
    int* blkoff  = blksum + 256;                        // 256
    float* Wt    = (float*)(((uintptr_t)(blkoff + 256) + 255) & ~(uintptr_t)255); // n_node*128

    int nb = (N + 255) / 256;   // 125

    k_wt<<<128, 256, 0, stream>>>(W_ih1, Wt, n_node);
    k_zero<<<(N + 255) / 256, 256, 0, stream>>>(deg, N);
    k_hist<<<(E + 255) / 256, 256, 0, stream>>>(dst, deg, E);
    k_scan1<<<nb, 256, 0, stream>>>(deg, blksum, N);
    k_scan2<<<1, 256, 0, stream>>>(blksum, blkoff, nb);
    k_scan3<<<nb, 256, 0, stream>>>(deg, blkoff, rowptr, cursor, N, E);
    k_scatter<<<(E + 255) / 256, 256, 0, stream>>>(src, dst, cursor, csr_src, E);
    k_pre<<<1, 256, 0, stream>>>(W_gat, a_src, a_dst, wa);
    k_att<<<N / 32, 256, 0, stream>>>(x, wa, asrc, adst);
    k_gat<<<(N * 64 + 255) / 256, 256, 0, stream>>>(rowptr, csr_src, asrc, adst,
                                                    x, z, N);
    k_zw<<<2000, 256, 0, stream>>>(z, W_gat, b_gat, gatT, N, n_node);
    k_p1<<<B * 16, 256, 0, stream>>>(gatT, Wt, b_ih1, b_hh1, P1, n_node, B);
    k_lstm<<<B, 640, 0, stream>>>(P1, W_hh1, W_ih2, W_hh2, b_ih2, b_hh2,
                                  h2finT, B, T);
    k_fin<<<B * 8, 256, 0, stream>>>(h2finT, W_lin, b_lin, (float*)d_out, n_node, B);
}

// Round 5
// 228.294 us; speedup vs baseline: 1.0505x; 1.0505x over previous
//
#include <hip/hip_runtime.h>
#include <hip/hip_fp16.h>
#include <math.h>

#define NEG_SLOPE 0.2f

__device__ __forceinline__ float sigm(float x) { return 1.0f / (1.0f + __expf(-x)); }
__device__ __forceinline__ float tanh_fast(float x) {
    float xc = fminf(fmaxf(x, -15.0f), 15.0f);
    float e2 = __expf(2.0f * xc);
    return (e2 - 1.0f) / (e2 + 1.0f);
}
__device__ __forceinline__ float lrelu(float x) { return (x > 0.0f) ? x : NEG_SLOPE * x; }

typedef _Float16 h2v __attribute__((ext_vector_type(2)));
__device__ __forceinline__ float fdot2h(h2v a, h2v b, float c) {
#if __has_builtin(__builtin_amdgcn_fdot2)
    return __builtin_amdgcn_fdot2(a, b, c, false);
#else
    return (float)a[0] * (float)b[0] + (float)a[1] * (float)b[1] + c;
#endif
}

// ---------------- K0: zero deg ----------------
__global__ void k_zero(int* __restrict__ deg, int N) {
    int i = blockIdx.x * 256 + threadIdx.x;
    if (i < N) deg[i] = 0;
}

// ---------------- K1: histogram of dst ----------------
__global__ void k_hist(const int* __restrict__ dst, int* __restrict__ deg, int E) {
    int e = blockIdx.x * 256 + threadIdx.x;
    if (e < E) atomicAdd(deg + dst[e], 1);
}

// ---------------- scan (3 kernels, multi-block) ----------------
__global__ __launch_bounds__(256) void k_scan1(const int* __restrict__ deg,
                                               int* __restrict__ blksum, int N) {
    __shared__ int s[256];
    int tid = threadIdx.x;
    int i = blockIdx.x * 256 + tid;
    int v = (i < N) ? deg[i] : 0;
    s[tid] = v;
    __syncthreads();
    #pragma unroll
    for (int off = 128; off > 0; off >>= 1) {
        if (tid < off) s[tid] += s[tid + off];
        __syncthreads();
    }
    if (tid == 0) blksum[blockIdx.x] = s[0];
}

__global__ __launch_bounds__(256) void k_scan2(const int* __restrict__ blksum,
                                               int* __restrict__ blkoff, int nb) {
    __shared__ int s[256];
    int tid = threadIdx.x;
    int v = (tid < nb) ? blksum[tid] : 0;
    s[tid] = v;
    __syncthreads();
    for (int off = 1; off < 256; off <<= 1) {
        int t = (tid >= off) ? s[tid - off] : 0;
        __syncthreads();
        s[tid] += t;
        __syncthreads();
    }
    if (tid < nb) blkoff[tid] = s[tid] - v;   // exclusive
}

__global__ __launch_bounds__(256) void k_scan3(const int* __restrict__ deg,
                                               const int* __restrict__ blkoff,
                                               int* __restrict__ rowptr,
                                               int* __restrict__ cursor, int N, int E) {
    __shared__ int s[256];
    int tid = threadIdx.x;
    int i = blockIdx.x * 256 + tid;
    int v = (i < N) ? deg[i] : 0;
    s[tid] = v;
    __syncthreads();
    for (int off = 1; off < 256; off <<= 1) {
        int t = (tid >= off) ? s[tid - off] : 0;
        __syncthreads();
        s[tid] += t;
        __syncthreads();
    }
    int excl = s[tid] - v + blkoff[blockIdx.x];
    if (i < N) { rowptr[i] = excl; cursor[i] = excl; }
    if (i == N - 1) rowptr[N] = E;
}

// ---------------- K3: scatter edges into CSR (by dst) ----------------
__global__ void k_scatter(const int* __restrict__ src, const int* __restrict__ dst,
                          int* __restrict__ cursor, int* __restrict__ csr_src, int E) {
    int e = blockIdx.x * 256 + threadIdx.x;
    if (e < E) {
        int pos = atomicAdd(cursor + dst[e], 1);
        csr_src[pos] = src[e];
    }
}

// ---------------- K4a: wa_src[k][h] ----------------
__global__ void k_pre(const float* __restrict__ W_gat, const float* __restrict__ a_src,
                      const float* __restrict__ a_dst, float* __restrict__ wa) {
    int tid = threadIdx.x;          // tid = k*8 + h
    int k = tid >> 3, h = tid & 7;
    float s1 = 0.0f, s2 = 0.0f;
    for (int c = 0; c < 32; ++c) {
        float wv = W_gat[k * 256 + h * 32 + c];
        s1 += wv * a_src[h * 32 + c];
        s2 += wv * a_dst[h * 32 + c];
    }
    wa[tid] = s1;
    wa[256 + tid] = s2;
}

// ---------------- K4b: asrc/adst = x @ wa ----------------
__global__ __launch_bounds__(256) void k_att(const float* __restrict__ x,
                                             const float* __restrict__ wa,
                                             float* __restrict__ asrc,
                                             float* __restrict__ adst) {
    __shared__ float xs[32 * 33];
    __shared__ float was[256], wad[256];
    int tid = threadIdx.x;
    int n0 = blockIdx.x * 32;
    for (int i = tid; i < 1024; i += 256) {
        int nl = i >> 5, k = i & 31;
        xs[nl * 33 + k] = x[(size_t)(n0 + nl) * 32 + k];
    }
    was[tid] = wa[tid];
    wad[tid] = wa[256 + tid];
    __syncthreads();
    int nl = tid >> 3, h = tid & 7;
    float s1 = 0.0f, s2 = 0.0f;
    #pragma unroll
    for (int k = 0; k < 32; ++k) {
        float xv = xs[nl * 33 + k];
        s1 += xv * was[k * 8 + h];
        s2 += xv * wad[k * 8 + h];
    }
    asrc[(size_t)(n0 + nl) * 8 + h] = s1;
    adst[(size_t)(n0 + nl) * 8 + h] = s2;
}

// ---------------- K5: GAT gather ----------------
__global__ __launch_bounds__(256) void k_gat(
    const int* __restrict__ rowptr, const int* __restrict__ csr_src,
    const float* __restrict__ asrc, const float* __restrict__ adst,
    const float* __restrict__ x, float* __restrict__ z, int N) {
    int w = (blockIdx.x * 256 + threadIdx.x) >> 6;
    int lane = threadIdx.x & 63;
    if (w >= N) return;
    int r0 = rowptr[w], r1 = rowptr[w + 1];
    int h = lane >> 3, kq = lane & 7;
    float ad = adst[w * 8 + h];
    float4 acc = make_float4(0.0f, 0.0f, 0.0f, 0.0f);
    float den = 0.0f;
    const float4* x4 = (const float4*)x;
    for (int i = r0; i < r1; ++i) {
        int s = csr_src[i];
        float ew = __expf(lrelu(asrc[s * 8 + h] + ad));
        float4 xv = x4[(size_t)s * 8 + kq];
        acc.x += ew * xv.x; acc.y += ew * xv.y;
        acc.z += ew * xv.z; acc.w += ew * xv.w;
        den += ew;
    }
    float inv = 1.0f / fmaxf(den, 1e-16f);
    float4 r = make_float4(acc.x * inv, acc.y * inv, acc.z * inv, acc.w * inv);
    ((float4*)z)[(size_t)w * 64 + lane] = r;
}

// ---------------- K5b: gatT[b][c][node] = z[node,:] @ M[:,c] + b_gat[c] ----------------
__global__ __launch_bounds__(256) void k_zw(
    const float* __restrict__ z, const float* __restrict__ W_gat,
    const float* __restrict__ b_gat, float* __restrict__ gatT, int N, int n_node) {
    int gw = (blockIdx.x * 256 + threadIdx.x) >> 6;  // 0..7999
    int lane = threadIdx.x & 63;
    int chalf = gw & 1;
    int nset = gw >> 1;                               // 0..3999
    int c = chalf * 16 + (lane & 15);
    int sl = lane >> 4;
    float wcol[64];
    #pragma unroll
    for (int i = 0; i < 64; ++i) {
        int k = i & 31, hh = sl * 2 + (i >> 5);
        wcol[i] = 0.125f * W_gat[k * 256 + hh * 32 + c];
    }
    float bg = b_gat[c];
    const float4* z4 = (const float4*)z;
    for (int it = 0; it < 8; ++it) {
        int n = nset * 8 + it;
        if (n >= N) break;
        float p = 0.0f;
        #pragma unroll
        for (int k4 = 0; k4 < 16; ++k4) {
            float4 zv = z4[(size_t)n * 64 + sl * 16 + k4];
            p += zv.x * wcol[4 * k4] + zv.y * wcol[4 * k4 + 1]
               + zv.z * wcol[4 * k4 + 2] + zv.w * wcol[4 * k4 + 3];
        }
        p += __shfl_xor(p, 16, 64);
        p += __shfl_xor(p, 32, 64);
        if (lane < 16) {
            int b = n / n_node, kk = n - b * n_node;
            gatT[((size_t)b * 32 + c) * n_node + kk] = p + bg;
        }
    }
}

// ---------------- K6a: transpose W_ih1 [128][n_node] -> Wt [n_node][128] ----------------
__global__ __launch_bounds__(256) void k_wt(const float* __restrict__ W,
                                            float* __restrict__ Wt, int n_node) {
    __shared__ float tle[32][33];
    int kt = blockIdx.x & 31;
    int gt = blockIdx.x >> 5;
    int tid = threadIdx.x;
    for (int i = tid; i < 1024; i += 256) {
        int gl = i >> 5, kl = i & 31;
        int g = gt * 32 + gl, k = kt * 32 + kl;
        tle[gl][kl] = (k < n_node) ? W[(size_t)g * n_node + k] : 0.0f;
    }
    __syncthreads();
    for (int i = tid; i < 1024; i += 256) {
        int kl = i >> 5, gl = i & 31;
        int k = kt * 32 + kl, g = gt * 32 + gl;
        if (k < n_node) Wt[(size_t)k * 128 + g] = tle[gl][kl];
    }
}

// ---------------- K6c: pack LSTM2 weights for coalesced per-thread-row preload ----------------
// Thread tid2 in k_lstm owns row g_idx = (tid2&3)*128 + (tid2>>2).
// wpack[j][tid2] (uint4)  = fp16{ W_hh2[g_idx][8j .. 8j+7] },  j in [0,16)
// wipack[j][tid2] (float4)=      W_ih2[g_idx][4j .. 4j+3],     j in [0,8)
__global__ __launch_bounds__(256) void k_pack2(
    const float* __restrict__ W_hh2, const float* __restrict__ W_ih2,
    uint4* __restrict__ wpack, float4* __restrict__ wipack) {
    int i = blockIdx.x * 256 + threadIdx.x;   // 0..8191
    int j = i >> 9, t2 = i & 511;
    int g = (t2 & 3) * 128 + (t2 >> 2);
    const float* p = W_hh2 + (size_t)g * 128 + j * 8;
    __align__(16) _Float16 tmp[8];
    #pragma unroll
    for (int k = 0; k < 8; ++k) tmp[k] = (_Float16)p[k];
    wpack[j * 512 + t2] = *(const uint4*)tmp;
    if (j < 8) {
        const float4* q = (const float4*)(W_ih2 + (size_t)g * 32) + j;
        wipack[j * 512 + t2] = *q;
    }
}

// ---------------- K6b: P1[t,b,g] = bias + dot(Wt[:, g], gatT[b][t][:]) ----------------
__global__ __launch_bounds__(256) void k_p1(
    const float* __restrict__ gatT, const float* __restrict__ Wt,
    const float* __restrict__ b_ih1, const float* __restrict__ b_hh1,
    float* __restrict__ P1, int n_node, int B) {
    __shared__ __align__(16) float Arow[2][1024];
    __shared__ __align__(16) float part[4][2][128];
    int blk = blockIdx.x;
    int b = blk >> 4;
    int tq = blk & 15;
    int tid = threadIdx.x;
    const float* A0 = gatT + ((size_t)b * 32 + tq * 2) * n_node;
    #pragma unroll
    for (int r = 0; r < 2; ++r)
        for (int i = tid; i < n_node; i += 256)
            Arow[r][i] = A0[(size_t)r * n_node + i];
    __syncthreads();

    int g4 = tid & 31;               // float4 column group: g = g4*4..+3
    int tloc = (tid >> 5) & 1;
    int ks = tid >> 6;               // wave id = k-quarter
    int kq = n_node >> 2;            // 250
    int k0 = ks * kq;
    const float4* Wt4 = (const float4*)Wt;
    float4 acc = make_float4(0.0f, 0.0f, 0.0f, 0.0f);
    #pragma unroll 4
    for (int k = 0; k < kq; ++k) {
        float4 w = Wt4[(size_t)(k0 + k) * 32 + g4];
        float a = Arow[tloc][k0 + k];
        acc.x += w.x * a; acc.y += w.y * a;
        acc.z += w.z * a; acc.w += w.w * a;
    }
    *(float4*)&part[ks][tloc][g4 * 4] = acc;
    __syncthreads();

    int tl = tid >> 7, g = tid & 127;
    float s = part[0][tl][g] + part[1][tl][g] + part[2][tl][g] + part[3][tl][g]
            + b_ih1[g] + b_hh1[g];
    int t = tq * 2 + tl;
    P1[((size_t)t * B + b) * 128 + g] = s;
}

// ---------------- K7: pipelined LSTM1 || LSTM2, spill-free + coalesced preload ----------------
// 640 threads = 10 waves, __launch_bounds__(640,3): 10-wave block forces 3 waves/SIMD,
// so allow up to ~170 VGPR -> no scratch spill of the register-resident weights
// (R4: VGPR=84 + WRITE_SIZE 1056KB = spill on the critical path).
// Waves 0-1: LSTM1, lane-adjacent gate map r1=(tid&3)*32+(tid>>2), 3x shfl_xor, h1d
// double-buffered -> no second barrier. Waves 2-9: LSTM2 row g_idx=(tid2&3)*128+(tid2>>2),
// weights preloaded COALESCED from wpack/wipack (16B/lane consecutive).
// ONE __syncthreads per superstep; 33 supersteps.
__global__ __launch_bounds__(640, 3) void k_lstm(
    const float* __restrict__ P1, const float* __restrict__ W_hh1,
    const uint4* __restrict__ wpack, const float4* __restrict__ wipack,
    const float* __restrict__ b_ih2, const float* __restrict__ b_hh2,
    float* __restrict__ h2finT, int B, int T) {
    __shared__ __align__(16) float P1s[32][128];     // 16KB
    __shared__ __align__(16) float h1d[2][32];       // double-buffered L1 state
    __shared__ __align__(16) float h1all[32][32];    // 4KB (for L2 input proj)
    __shared__ __align__(16) __half hbuf[2][128];
    int tid = threadIdx.x, b = blockIdx.x;

    for (int i = tid; i < 4096; i += 640) {
        int t = i >> 7, g = i & 127;
        P1s[t][g] = P1[((size_t)t * B + b) * 128 + g];
    }

    // L1 (waves 0-1): gate row r1, lane-adjacent gates of unit n1
    int n1 = (tid >> 2) & 31, gt1 = tid & 3;
    int r1 = gt1 * 32 + n1;
    float4 w1[8];
    float c1 = 0.0f;
    if (tid < 128) {
        const float4* W = (const float4*)(W_hh1 + (size_t)r1 * 32);
        #pragma unroll
        for (int j = 0; j < 8; ++j) w1[j] = W[j];
    }

    // L2 (waves 2-9): packed fp16 W_hh2 row + f32 W_ih2 row, coalesced loads
    int tid2 = tid - 128;
    int gt = tid2 & 3, n = tid2 >> 2;
    int g_idx = gt * 128 + n;
    uint4 whq[16];
    float4 wi[8];
    float bias = 0.0f, c2 = 0.0f;
    if (tid >= 128) {
        #pragma unroll
        for (int j = 0; j < 16; ++j) whq[j] = wpack[j * 512 + tid2];
        #pragma unroll
        for (int j = 0; j < 8; ++j) wi[j] = wipack[j * 512 + tid2];
        bias = b_ih2[g_idx] + b_hh2[g_idx];
    }

    if (tid < 32) h1d[0][tid] = 0.0f;
    if (tid >= 128 && tid < 256) hbuf[0][tid - 128] = __float2half(0.0f);
    __syncthreads();

    for (int s = 0; s <= T; ++s) {
        if (tid < 128) {
            if (s < T) {
                float acc = P1s[s][r1];
                const float4* hp = (const float4*)h1d[s & 1];
                #pragma unroll
                for (int j = 0; j < 8; ++j) {
                    float4 h = hp[j], w = w1[j];
                    acc += w.x * h.x + w.y * h.y + w.z * h.z + w.w * h.w;
                }
                float v1 = __shfl_xor(acc, 1, 64);
                float v2 = __shfl_xor(acc, 2, 64);
                float v3 = __shfl_xor(acc, 3, 64);
                if (gt1 == 0) {
                    float i_ = sigm(acc), f_ = sigm(v1);
                    float g_ = tanh_fast(v2), o_ = sigm(v3);
                    c1 = f_ * c1 + i_ * g_;
                    float h = o_ * tanh_fast(c1);
                    h1d[(s + 1) & 1][n1] = h;
                    h1all[s][n1] = h;
                }
            }
        } else if (s >= 1) {
            int t2s = s - 1;
            // input projection on the fly (broadcast reads of h1all[t2s])
            const float4* hp1 = (const float4*)h1all[t2s];
            float p = bias;
            #pragma unroll
            for (int j = 0; j < 8; ++j) {
                float4 w = wi[j], h = hp1[j];
                p += w.x * h.x + w.y * h.y + w.z * h.z + w.w * h.w;
            }
            // recurrent 128-dot in fp16, 8 independent chains
            const uint4* hc4 = (const uint4*)hbuf[t2s & 1];
            float a0 = 0.0f, a1 = 0.0f, a2 = 0.0f, a3 = 0.0f;
            float a4 = 0.0f, a5 = 0.0f, a6 = 0.0f, a7 = 0.0f;
            #pragma unroll
            for (int j = 0; j < 16; j += 2) {
                uint4 hvA = hc4[j], hvB = hc4[j + 1];
                const h2v* ha = reinterpret_cast<const h2v*>(&hvA);
                const h2v* hb = reinterpret_cast<const h2v*>(&hvB);
                const h2v* wa_ = reinterpret_cast<const h2v*>(&whq[j]);
                const h2v* wb_ = reinterpret_cast<const h2v*>(&whq[j + 1]);
                a0 = fdot2h(wa_[0], ha[0], a0);
                a1 = fdot2h(wa_[1], ha[1], a1);
                a2 = fdot2h(wa_[2], ha[2], a2);
                a3 = fdot2h(wa_[3], ha[3], a3);
                a4 = fdot2h(wb_[0], hb[0], a4);
                a5 = fdot2h(wb_[1], hb[1], a5);
                a6 = fdot2h(wb_[2], hb[2], a6);
                a7 = fdot2h(wb_[3], hb[3], a7);
            }
            float acc = p + (((a0 + a1) + (a2 + a3)) + ((a4 + a5) + (a6 + a7)));
            float v1 = __shfl_xor(acc, 1, 64);
            float v2 = __shfl_xor(acc, 2, 64);
            float v3 = __shfl_xor(acc, 3, 64);
            if (gt == 0) {
                float i_ = sigm(acc), f_ = sigm(v1);
                float g_ = tanh_fast(v2), o_ = sigm(v3);
                c2 = f_ * c2 + i_ * g_;
                float h = o_ * tanh_fast(c2);
                hbuf[(t2s + 1) & 1][n] = __float2half(h);
                if (t2s == T - 1) h2finT[n * 32 + b] = h;
            }
        }
        __syncthreads();
    }
}

// ---------------- K8: final linear from h2finT ----------------
__global__ __launch_bounds__(256) void k_fin(
    const float* __restrict__ h2finT, const float* __restrict__ W_lin,
    const float* __restrict__ b_lin, float* __restrict__ out, int n_node, int B) {
    __shared__ __align__(16) float hs[128];
    int b = blockIdx.x >> 3;
    int kc = blockIdx.x & 7;
    int tid = threadIdx.x;
    if (tid < 128) hs[tid] = h2finT[tid * 32 + b];
    __syncthreads();
    int outdim = n_node * 2;
    int kk = kc * 256 + tid;
    if (kk < outdim) {
        float acc = b_lin[kk];
        const float4* W4 = (const float4*)(W_lin + (size_t)kk * 128);
        const float4* h4 = (const float4*)hs;
        #pragma unroll 8
        for (int j = 0; j < 32; ++j) {
            float4 w = W4[j], h = h4[j];
            acc += w.x * h.x + w.y * h.y + w.z * h.z + w.w * h.w;
        }
        out[(size_t)b * outdim + kk] = acc;
    }
}

extern "C" void kernel_launch(void* const* d_in, const int* in_sizes, int n_in,
                              void* d_out, int out_size, void* d_ws, size_t ws_size,
                              hipStream_t stream) {
    const float* x     = (const float*)d_in[0];
    const int*   src   = (const int*)d_in[1];
    const int*   dst   = (const int*)d_in[2];
    const float* W_gat = (const float*)d_in[4];
    const float* a_src = (const float*)d_in[5];
    const float* a_dst = (const float*)d_in[6];
    const float* b_gat = (const float*)d_in[7];
    const float* W_ih1 = (const float*)d_in[8];
    const float* W_hh1 = (const float*)d_in[9];
    const float* b_ih1 = (const float*)d_in[10];
    const float* b_hh1 = (const float*)d_in[11];
    const float* W_ih2 = (const float*)d_in[12];
    const float* W_hh2 = (const float*)d_in[13];
    const float* b_ih2 = (const float*)d_in[14];
    const float* b_hh2 = (const float*)d_in[15];
    const float* W_lin = (const float*)d_in[16];
    const float* b_lin = (const float*)d_in[17];

    int N = in_sizes[0] / 32;          // 32000
    int E = in_sizes[1];               // 384000
    int n_node = in_sizes[8] / 128;    // 1000
    int B = N / n_node;                // 32
    int T = 32;

    float* ws = (float*)d_ws;
    float* z      = ws;                                 // N*256
    float* asrc   = z + (size_t)N * 256;                // N*8
    float* adst   = asrc + (size_t)N * 8;               // N*8
    float* gatT   = adst + (size_t)N * 8;               // N*32
    float* P1     = gatT + (size_t)N * 32;              // T*B*128
    float* wpackf = P1 + (size_t)T * B * 128;           // 128KB: packed fp16 W_hh2
    float* wipackf= wpackf + 32768;                     // 64KB: packed f32 W_ih2
    float* h2finT = wipackf + 16384;                    // 128*32
    float* wa     = h2finT + 128 * 32;                  // 512
    int* deg     = (int*)(wa + 512);                    // N
    int* cursor  = deg + N;                             // N
    int* rowptr  = cursor + N;                          // N+1
    int* csr_src = rowptr + N + 1;                      // E
    int* blksum  = csr_src + E;                         // 256
    int* blkoff  = blksum + 256;                        // 256
    float* Wt    = (float*)(((uintptr_t)(blkoff + 256) + 255) & ~(uintptr_t)255); // n_node*128

    uint4*  wpack  = (uint4*)wpackf;
    float4* wipack = (float4*)wipackf;

    int nb = (N + 255) / 256;   // 125

    k_pack2<<<32, 256, 0, stream>>>(W_hh2, W_ih2, wpack, wipack);
    k_wt<<<128, 256, 0, stream>>>(W_ih1, Wt, n_node);
    k_zero<<<(N + 255) / 256, 256, 0, stream>>>(deg, N);
    k_hist<<<(E + 255) / 256, 256, 0, stream>>>(dst, deg, E);
    k_scan1<<<nb, 256, 0, stream>>>(deg, blksum, N);
    k_scan2<<<1, 256, 0, stream>>>(blksum, blkoff, nb);
    k_scan3<<<nb, 256, 0, stream>>>(deg, blkoff, rowptr, cursor, N, E);
    k_scatter<<<(E + 255) / 256, 256, 0, stream>>>(src, dst, cursor, csr_src, E);
    k_pre<<<1, 256, 0, stream>>>(W_gat, a_src, a_dst, wa);
    k_att<<<N / 32, 256, 0, stream>>>(x, wa, asrc, adst);
    k_gat<<<(N * 64 + 255) / 256, 256, 0, stream>>>(rowptr, csr_src, asrc, adst,
                                                    x, z, N);
    k_zw<<<2000, 256, 0, stream>>>(z, W_gat, b_gat, gatT, N, n_node);
    k_p1<<<B * 16, 256, 0, stream>>>(gatT, Wt, b_ih1, b_hh1, P1, n_node, B);
    k_lstm<<<B, 640, 0, stream>>>(P1, W_hh1, wpack, wipack, b_ih2, b_hh2,
                                  h2finT, B, T);
    k_fin<<<B * 8, 256, 0, stream>>>(h2finT, W_lin, b_lin, (float*)d_out, n_node, B);
}